// Round 12
// baseline (1822.253 us; speedup 1.0000x reference)
//
#include <hip/hip_runtime.h>
#include <hip/hip_bf16.h>
#include <math.h>
#include <stdint.h>

#define N_NODES 100000
#define N_EDGES 3200000
#define D 64
#define NUM_RELS 20
#define HID_ATTR 32
#define OUT_ATTR 10
#define PADR 72                          // A-tile row stride in bf16 (144 B)
#define NFB (N_NODES / 16)               // 6250 fused blocks (16 nodes each)

// two-level MSD counting sort (R8 structure, best measured)
#define BUCKET_DSTS 256                  // dsts per coarse bucket (dst >> 8)
#define NB 391                           // ceil(100000 / 256)
#define PA_THREADS 512
#define PA_EPT 16                        // edges per thread
#define PA_CHUNK (PA_THREADS * PA_EPT)   // 8192
#define PA_GRID 391                      // ceil(3.2M / 8192)
#define PB_BINS (BUCKET_DSTS * NUM_RELS) // 5120 fine bins per bucket

// prep kernel block partition: [0,NB) hist | [NB,NB+F2B) f2b | wconv
#define F2B_BLOCKS 3125                  // 1,600,000 float4 / 512
#define WC_BLOCKS (2 * NUM_RELS)
#define PREP_GRID (NB + F2B_BLOCKS + WC_BLOCKS)

typedef __attribute__((ext_vector_type(8))) short bf16x8;
typedef __attribute__((ext_vector_type(4))) float f32x4;

static __device__ __forceinline__ unsigned short f2bf(float x) {
    unsigned u = __builtin_bit_cast(unsigned, x);
    unsigned r = (u + 0x7FFFu + ((u >> 16) & 1u)) >> 16;
    return (unsigned short)r;
}
static __device__ __forceinline__ float bf2f_lo(unsigned u) {
    return __builtin_bit_cast(float, u << 16);
}
static __device__ __forceinline__ float bf2f_hi(unsigned u) {
    return __builtin_bit_cast(float, u & 0xFFFF0000u);
}
// packed f32->bf16 RNE (bit-identical to f2bf above for finite inputs)
static __device__ __forceinline__ unsigned cvt_pk_bf16(float lo, float hi) {
    unsigned r;
    asm("v_cvt_pk_bf16_f32 %0, %1, %2" : "=v"(r) : "v"(lo), "v"(hi));
    return r;
}

// ---------------- prep: hist + f2b + wconv in ONE launch (independent work)
__global__ __launch_bounds__(512) void prep_kernel(
    const int* __restrict__ dst, int* __restrict__ hist,
    const float* __restrict__ hin, unsigned short* __restrict__ xb,
    const float* __restrict__ W1, const float* __restrict__ W2,
    unsigned short* __restrict__ w1b, unsigned short* __restrict__ w2b) {
    int bid = blockIdx.x;
    if (bid < NB) {
        // ---- histogram of dst>>8 over this block's edge chunk
        __shared__ int h[NB];
        for (int i = threadIdx.x; i < NB; i += 512) h[i] = 0;
        __syncthreads();
        int base = bid * PA_CHUNK;
#pragma unroll
        for (int k = 0; k < PA_EPT; ++k) {
            int e = base + k * 512 + threadIdx.x;
            if (e < N_EDGES) atomicAdd(&h[dst[e] >> 8], 1);
        }
        __syncthreads();
        for (int i = threadIdx.x; i < NB; i += 512)
            if (h[i]) atomicAdd(&hist[i], h[i]);
    } else if (bid < NB + F2B_BLOCKS) {
        // ---- f32 -> bf16 node features (float4 granularity)
        int i = (bid - NB) * 512 + threadIdx.x;   // < 1,600,000 exactly
        float4 v = ((const float4*)hin)[i];
        ushort4 o;
        o.x = f2bf(v.x); o.y = f2bf(v.y); o.z = f2bf(v.z); o.w = f2bf(v.w);
        ((ushort4*)xb)[i] = o;
    } else {
        // ---- W[r][d][o] fp32 -> Wb[r][o][d] bf16 (B-frag layout, verified)
        int r = bid - (NB + F2B_BLOCKS);
        const float* Ws = (r < NUM_RELS) ? W1 + (size_t)r * (D * D)
                                         : W2 + (size_t)(r - NUM_RELS) * (D * D);
        unsigned short* Wd = (r < NUM_RELS) ? w1b + (size_t)r * (D * D)
                                            : w2b + (size_t)(r - NUM_RELS) * (D * D);
        for (int i = threadIdx.x; i < D * D; i += 512) {
            int d2 = i >> 6, o = i & 63;
            Wd[o * D + d2] = f2bf(Ws[d2 * D + o]);
        }
    }
}

// ---------------- scan of 391 bucket counts; also zeroes gpart+done ----
__global__ void scan_bucket_kernel(const int* __restrict__ hist, int* __restrict__ bbase,
                                   int* __restrict__ bcur, int* __restrict__ sched_off,
                                   int* __restrict__ gpart_i) {
    __shared__ int s[512];
    int t = threadIdx.x;
    for (int i = t; i < 2049; i += 512) gpart_i[i] = 0;   // gpart[32][64] + done
    int v = (t < NB) ? hist[t] : 0;
    s[t] = v;
    __syncthreads();
    for (int d2 = 1; d2 < 512; d2 <<= 1) {
        int x = (t >= d2) ? s[t - d2] : 0;
        __syncthreads();
        s[t] += x;
        __syncthreads();
    }
    if (t < NB) {
        int b = s[t] - v;
        bbase[t] = b;
        bcur[t] = b;
    }
    if (t == 0) {
        bbase[NB] = N_EDGES;
        sched_off[NFB * 32] = N_EDGES;   // global sentinel
    }
}

__global__ __launch_bounds__(PA_THREADS) void passA_kernel(
    const int* __restrict__ src, const int* __restrict__ dst,
    const int* __restrict__ etype, int* __restrict__ bcur,
    unsigned* __restrict__ tmp) {
    __shared__ int h[NB];   // block histogram
    __shared__ int gb[NB];  // global segment base for this block
    __shared__ int c[NB];   // running within-segment count
    for (int i = threadIdx.x; i < NB; i += PA_THREADS) h[i] = 0;
    __syncthreads();
    int base = blockIdx.x * PA_CHUNK;
    int d[PA_EPT];
#pragma unroll
    for (int k = 0; k < PA_EPT; ++k) {
        int e = base + k * PA_THREADS + threadIdx.x;
        d[k] = (e < N_EDGES) ? dst[e] : -1;
        if (d[k] >= 0) atomicAdd(&h[d[k] >> 8], 1);
    }
    __syncthreads();
    for (int i = threadIdx.x; i < NB; i += PA_THREADS) {
        int n = h[i];
        gb[i] = n ? atomicAdd(&bcur[i], n) : 0;
        c[i] = 0;
    }
    __syncthreads();
#pragma unroll
    for (int k = 0; k < PA_EPT; ++k) {
        int e = base + k * PA_THREADS + threadIdx.x;
        if (d[k] >= 0) {
            int b = d[k] >> 8;
            int sv = src[e], r = etype[e];
            int pos = gb[b] + atomicAdd(&c[b], 1);
            tmp[pos] = ((unsigned)(d[k] & 255) << 22) | ((unsigned)sv << 5) | (unsigned)r;
        }
    }
}

__global__ __launch_bounds__(512) void passB_kernel(
    const unsigned* __restrict__ tmp, const int* __restrict__ bbase,
    unsigned* __restrict__ edgedata, int* __restrict__ sched_off) {
    __shared__ int binpos[PB_BINS];   // 20 KB: counts -> scheduled positions
    __shared__ int blen[PB_BINS];     // 20 KB: bin lengths (saved counts)
    __shared__ unsigned sk[16 * 64];  // 4 KB: per-fb sort keys (len<<8|wloc)
    __shared__ int swo[16 * 64];      // 4 KB: per-walk scheduled offset in fb
    __shared__ int gs[512];           // 2 KB: per-fb group-total scan
    __shared__ int ssum[512];         // 2 KB: bin scan partials
    __shared__ int fbb[16];           // fb base positions
    int t = threadIdx.x;
    int b = blockIdx.x;
    int beg = bbase[b], end = bbase[b + 1];
    for (int i = t; i < PB_BINS; i += 512) binpos[i] = 0;
    __syncthreads();
    for (int i = beg + t; i < end; i += 512) {
        unsigned v = tmp[i];
        int key = (int)(v >> 22) * NUM_RELS + (int)(v & 31u);
        atomicAdd(&binpos[key], 1);
    }
    __syncthreads();
    for (int i = t; i < PB_BINS; i += 512) blen[i] = binpos[i];
    __syncthreads();
    // exclusive scan of 5120 bins; thread t owns bins [t*10, t*10+10)
    int loc[10];
    int sum = 0;
#pragma unroll
    for (int j = 0; j < 10; ++j) {
        loc[j] = sum;
        sum += binpos[t * 10 + j];
    }
    ssum[t] = sum;
    __syncthreads();
    for (int d2 = 1; d2 < 512; d2 <<= 1) {
        int x = (t >= d2) ? ssum[t - d2] : 0;
        __syncthreads();
        ssum[t] += x;
        __syncthreads();
    }
    int tbase = beg + ((t > 0) ? ssum[t - 1] : 0);
#pragma unroll
    for (int j = 0; j < 10; ++j) binpos[t * 10 + j] = tbase + loc[j];
    __syncthreads();
    if (t < 16) fbb[t] = binpos[t * 320];
    __syncthreads();
    // walk lengths: walk = (node_local nl, quarter qt), wloc = nl*4+qt
    for (int w = t; w < 1024; w += 512) {
        int fb = w >> 6, wloc = w & 63;
        int nl = wloc >> 2, qt = wloc & 3;
        int b0 = (fb * 16 + nl) * NUM_RELS + qt * 5;
        int len = blen[b0] + blen[b0 + 1] + blen[b0 + 2] + blen[b0 + 3] + blen[b0 + 4];
        sk[fb * 64 + wloc] = ((unsigned)len << 8) | (unsigned)wloc;
    }
    // bitonic sort desc, 64 elements per fb, 32 comparators per fb
    {
        int fb = t >> 5, k = t & 31;
        unsigned* s = &sk[fb * 64];
        for (int size = 2; size <= 64; size <<= 1) {
            for (int stride = size >> 1; stride > 0; stride >>= 1) {
                __syncthreads();
                int i1 = ((k & ~(stride - 1)) << 1) | (k & (stride - 1));
                int i2 = i1 | stride;
                unsigned x = s[i1], y = s[i2];
                bool descb = (i1 & size) == 0;
                if (descb ? (x < y) : (x > y)) { s[i1] = y; s[i2] = x; }
            }
        }
    }
    __syncthreads();
    // fold-pair rank k with rank 63-k onto group slot k; scan group totals
    {
        int fb = t >> 5, k = t & 31;
        unsigned kA = sk[fb * 64 + k], kB = sk[fb * 64 + 63 - k];
        int lenA = (int)(kA >> 8), widA = (int)(kA & 63u);
        int lenB = (int)(kB >> 8), widB = (int)(kB & 63u);
        int tot = lenA + lenB;
        gs[t] = tot;
        __syncthreads();
        for (int d2 = 1; d2 < 32; d2 <<= 1) {
            int x = (k >= d2) ? gs[t - d2] : 0;
            __syncthreads();
            gs[t] += x;
            __syncthreads();
        }
        int gbase = gs[t] - tot;   // exclusive within fb
        swo[fb * 64 + widA] = gbase;
        swo[fb * 64 + widB] = gbase + lenA;
        int gfb = b * 16 + fb;
        if (gfb < NFB) sched_off[gfb * 32 + k] = fbb[fb] + gbase;
    }
    __syncthreads();
    // rewrite binpos to scheduled positions
    for (int i = t; i < PB_BINS; i += 512) {
        int node = i / 20, rel = i - node * 20;
        int fb = node >> 4, nl = node & 15;
        int qt = rel / 5, rr = rel - qt * 5;
        int wid = nl * 4 + qt;
        int base = fbb[fb] + swo[fb * 64 + wid];
        int b0 = node * 20 + qt * 5;
        for (int r = 0; r < rr; ++r) base += blen[b0 + r];
        binpos[i] = base;
    }
    __syncthreads();
    // scatter in schedule order with rowoff payload
    for (int i = beg + t; i < end; i += 512) {
        unsigned v = tmp[i];
        int dl = (int)(v >> 22), rel = (int)(v & 31u);
        int ro = rel * (16 * PADR) + (dl & 15) * PADR;
        int key = dl * NUM_RELS + rel;
        int pos = atomicAdd(&binpos[key], 1);
        edgedata[pos] = ((v >> 5) & 0x1FFFFu) | ((unsigned)ro << 17);
    }
}

// ---------------- fused layer (R8 gather/MFMA; mode 2 fuses colsum+MLP) ----
// Block = 16 dst nodes (= one fb), 8 waves. Group gidx = wave*4+grp in [0,32)
// processes the contiguous balanced span [sched_off[fb*32+gidx], +1).
// The random x-row gather is memory-system-bound (R5-R10 arc) — structure
// frozen at the R8 version. Tail merged via clamp + x=0 masking ->
// bit-identical numerics. mode 1: relu'd bf16 out. mode 2: fp32 out +
// per-block column-sum into gpart[32][64] (shfl-reduced, 32-sliced atomics)
// + last-done block (device-scope ticket) reduces gpart and runs the MLP.
__global__ __launch_bounds__(512, 6) void fused_layer(
    const unsigned short* __restrict__ xb, const unsigned short* __restrict__ Wb,
    const unsigned* __restrict__ edgedata, const int* __restrict__ sched_off,
    unsigned short* __restrict__ xbout, float* __restrict__ h2out, int mode,
    float* __restrict__ gpart, int* __restrict__ done_ctr,
    const float* __restrict__ A1w, const float* __restrict__ A1b,
    const float* __restrict__ A2w, const float* __restrict__ A2b,
    float* __restrict__ out_a, float invN) {
    __shared__ __align__(16) unsigned short A[NUM_RELS * 16 * PADR];  // 46080 B
    int wave = threadIdx.x >> 6, lane = threadIdx.x & 63;
    int grp = lane >> 4, l4 = lane & 15;
    int gidx = wave * 4 + grp;         // 0..31
    int colb = l4 * 4;                 // column base, 0..60

    int beg = sched_off[blockIdx.x * 32 + gidx];
    int end = sched_off[blockIdx.x * 32 + gidx + 1];

    for (int i = threadIdx.x; i < NUM_RELS * 16 * PADR / 8; i += 512)
        ((int4*)A)[i] = (int4){0, 0, 0, 0};

    int cnt = end - beg;
    int nb = (cnt + 3) >> 2;           // number of (padded) 4-edge batches
    int nbmax = max(nb, __shfl_xor(nb, 16));
    nbmax = max(nbmax, __shfl_xor(nbmax, 32));
    int endm1 = end - 1;

    float a0 = 0.f, a1 = 0.f, a2 = 0.f, a3 = 0.f;
    unsigned roprev = 0xFFFFFFFFu;
    unsigned short* Ac = A + (unsigned)colb;

    auto rowload = [&](unsigned ewv) -> uint2 {
        return *(const uint2*)(xb + ((ewv & 0x1FFFFu) << 6) + (unsigned)colb);
    };
    auto proc = [&](const unsigned (&ewc)[4], const uint2 (&xv)[4], int valid) {
#pragma unroll
        for (int j = 0; j < 4; ++j) {
            unsigned ro = ewc[j] >> 17;
            bool real = j < valid;
            unsigned mx = real ? xv[j].x : 0u;
            unsigned my = real ? xv[j].y : 0u;
            bool keep = (ro == roprev);
            a0 = (keep ? a0 : 0.f) + bf2f_lo(mx);
            a1 = (keep ? a1 : 0.f) + bf2f_hi(mx);
            a2 = (keep ? a2 : 0.f) + bf2f_lo(my);
            a3 = (keep ? a3 : 0.f) + bf2f_hi(my);
            uint2 o;
            o.x = cvt_pk_bf16(a0, a1);
            o.y = cvt_pk_bf16(a2, a3);
            *(uint2*)(Ac + ro) = o;
            roprev = ro;
        }
    };

    unsigned e0[4], e1[4], e2[4];
    uint2 v0[4], v1[4];
    if (nb > 0) {
#pragma unroll
        for (int j = 0; j < 4; ++j) e0[j] = edgedata[min(beg + j, endm1)];
    }
    if (nb > 1) {
#pragma unroll
        for (int j = 0; j < 4; ++j) e1[j] = edgedata[min(beg + 4 + j, endm1)];
    }
    if (nb > 2) {
#pragma unroll
        for (int j = 0; j < 4; ++j) e2[j] = edgedata[min(beg + 8 + j, endm1)];
    }
    if (nb > 0) {
#pragma unroll
        for (int j = 0; j < 4; ++j) v0[j] = rowload(e0[j]);
    }
    if (nb > 1) {
#pragma unroll
        for (int j = 0; j < 4; ++j) v1[j] = rowload(e1[j]);
    }
    __builtin_amdgcn_sched_barrier(0);
    __syncthreads();

#define PHASE(GG, EW0, EW2, XV0)                                              \
    {                                                                         \
        int gg = (GG);                                                        \
        if (gg < nbmax) {                                                     \
            unsigned ewc[4];                                                  \
            uint2 xvc[4];                                                     \
            _Pragma("unroll") for (int j = 0; j < 4; ++j) {                   \
                ewc[j] = EW0[j]; xvc[j] = XV0[j];                             \
            }                                                                 \
            if (gg + 3 < nb) {                                                \
                int lb = beg + (gg + 3) * 4;                                  \
                _Pragma("unroll") for (int j = 0; j < 4; ++j)                 \
                    EW0[j] = edgedata[min(lb + j, endm1)];                    \
            }                                                                 \
            if (gg + 2 < nb) {                                                \
                _Pragma("unroll") for (int j = 0; j < 4; ++j)                 \
                    XV0[j] = rowload(EW2[j]);                                 \
            }                                                                 \
            __builtin_amdgcn_sched_barrier(0);                                \
            if (gg < nb) proc(ewc, xvc, cnt - gg * 4);                        \
        }                                                                     \
    }

    for (int g = 0; g < nbmax; g += 6) {
        PHASE(g + 0, e0, e2, v0)
        PHASE(g + 1, e1, e0, v1)
        PHASE(g + 2, e2, e1, v0)
        PHASE(g + 3, e0, e2, v1)
        PHASE(g + 4, e1, e0, v0)
        PHASE(g + 5, e2, e1, v1)
    }
#undef PHASE
    __syncthreads();

    // waves 0-3: transform. wave w covers output columns w*16..w*16+15
    if (wave < 4) {
        int lrow = lane & 15, lhi = lane >> 4;
        f32x4 C = {0.f, 0.f, 0.f, 0.f};
        for (int q = 0; q < NUM_RELS; ++q) {
            const unsigned short* Arow = &A[(q * 16 + lrow) * PADR + lhi * 8];
            bf16x8 aa0 = *(const bf16x8*)(Arow);        // k = lhi*8 + j
            bf16x8 aa1 = *(const bf16x8*)(Arow + 32);   // k = 32 + lhi*8 + j
            const unsigned short* wrow = Wb + ((size_t)q << 12)
                                         + (size_t)(wave * 16 + lrow) * D + lhi * 8;
            bf16x8 b0 = *(const bf16x8*)(wrow);
            bf16x8 b1 = *(const bf16x8*)(wrow + 32);
            C = __builtin_amdgcn_mfma_f32_16x16x32_bf16(aa0, b0, C, 0, 0, 0);
            C = __builtin_amdgcn_mfma_f32_16x16x32_bf16(aa1, b1, C, 0, 0, 0);
        }
        // C/D: row = lhi*4 + reg (dst-local), col = wave*16 + lrow
#pragma unroll
        for (int reg = 0; reg < 4; ++reg) {
            int onode = blockIdx.x * 16 + lhi * 4 + reg;
            int col = wave * 16 + lrow;
            if (mode == 1)
                xbout[(size_t)onode * D + col] = f2bf(fmaxf(C[reg], 0.f));
            else
                h2out[(size_t)onode * D + col] = C[reg];
        }
        if (mode == 2) {
            // column partial: sum this wave's 16 nodes for col = wave*16+lrow
            float s = C[0] + C[1] + C[2] + C[3];
            s += __shfl_xor(s, 16);
            s += __shfl_xor(s, 32);
            if (lane < 16) {
                int col = wave * 16 + lane;
                atomicAdd(&gpart[(blockIdx.x & 31) * 64 + col], s);
            }
        }
    }

    if (mode == 2) {
        __threadfence();
        __shared__ int lastflag;
        __syncthreads();
        if (threadIdx.x == 0) {
            int tkt = atomicAdd(done_ctr, 1);
            lastflag = (tkt == NFB - 1) ? 1 : 0;
        }
        __syncthreads();
        if (lastflag) {
            __shared__ float sg[D];
            __shared__ float a1s[HID_ATTR];
            if (threadIdx.x < D) {
                float s = 0.f;
                for (int sl = 0; sl < 32; ++sl)
                    s += atomicAdd(&gpart[sl * 64 + threadIdx.x], 0.0f);
                sg[threadIdx.x] = s;
            }
            __syncthreads();
            if (threadIdx.x < HID_ATTR) {
                float acc = A1b[threadIdx.x];
#pragma unroll
                for (int d2 = 0; d2 < D; ++d2)
                    acc = fmaf(sg[d2] * invN, A1w[d2 * HID_ATTR + threadIdx.x], acc);
                a1s[threadIdx.x] = fmaxf(acc, 0.0f);
            }
            __syncthreads();
            if (threadIdx.x < OUT_ATTR) {
                float acc = A2b[threadIdx.x];
#pragma unroll
                for (int j = 0; j < HID_ATTR; ++j)
                    acc = fmaf(a1s[j], A2w[j * OUT_ATTR + threadIdx.x], acc);
                out_a[threadIdx.x] = 1.0f / (1.0f + expf(-acc));
            }
        }
    }
}

// ---------------- launch ----------------

extern "C" void kernel_launch(void* const* d_in, const int* in_sizes, int n_in,
                              void* d_out, int out_size, void* d_ws, size_t ws_size,
                              hipStream_t stream) {
    const float* h   = (const float*)d_in[0];
    const int* src   = (const int*)d_in[1];
    const int* dst   = (const int*)d_in[2];
    const int* etype = (const int*)d_in[3];
    const float* W1  = (const float*)d_in[4];
    const float* W2  = (const float*)d_in[5];
    const float* A1w = (const float*)d_in[6];
    const float* A1b = (const float*)d_in[7];
    const float* A2w = (const float*)d_in[8];
    const float* A2b = (const float*)d_in[9];

    float* out_h2 = (float*)d_out;
    float* out_a  = out_h2 + (size_t)N_NODES * D;

    // workspace layout (int offsets from d_ws; all buffers 16B-aligned)
    int* base       = (int*)d_ws;
    float* gpart    = (float*)base;               // 32*64 f32 + done ctr
    int* done_ctr   = base + 2048;                // 1 int (pad to 2112)
    int* hist_b     = base + 2112;                // 448 (NB padded)
    int* bbase      = base + 2560;                // 448 (NB+1)
    int* bcur       = base + 3008;                // 448
    int* sched_off  = base + 3456;                // 200,064 (NFB*32+1 padded)
    unsigned* tmp   = (unsigned*)(base + 203520); // 3,200,000
    unsigned* edgedata = (unsigned*)(base + 3403520); // 3,200,000
    unsigned short* xb  = (unsigned short*)(base + 6603520);   // 6.4M u16
    unsigned short* xb2 = (unsigned short*)(base + 9803520);   // 6.4M u16
    unsigned short* w1b = (unsigned short*)(base + 13003520);  // 81,920 u16
    unsigned short* w2b = (unsigned short*)(base + 13044480);  // 81,920 u16
    // total: 13,085,440 ints = 52.3 MB

    hipMemsetAsync(hist_b, 0, NB * sizeof(int), stream);

    // prep: histogram + f2b + wconv (independent work, one launch)
    prep_kernel<<<PREP_GRID, 512, 0, stream>>>(dst, hist_b, h, xb,
                                               W1, W2, w1b, w2b);
    // scan (also zeroes gpart + done)
    scan_bucket_kernel<<<1, 512, 0, stream>>>(hist_b, bbase, bcur, sched_off,
                                              (int*)gpart);
    passA_kernel<<<PA_GRID, PA_THREADS, 0, stream>>>(src, dst, etype, bcur, tmp);
    passB_kernel<<<NB, 512, 0, stream>>>(tmp, bbase, edgedata, sched_off);

    // two fused RGCN layers; layer 2 fuses column-sum + MLP readout
    fused_layer<<<NFB, 512, 0, stream>>>(xb, w1b, edgedata, sched_off,
                                         xb2, nullptr, 1,
                                         nullptr, nullptr,
                                         nullptr, nullptr, nullptr, nullptr,
                                         nullptr, 0.f);
    fused_layer<<<NFB, 512, 0, stream>>>(xb2, w2b, edgedata, sched_off,
                                         nullptr, out_h2, 2,
                                         gpart, done_ctr,
                                         A1w, A1b, A2w, A2b,
                                         out_a, 1.0f / (float)N_NODES);
}

// Round 13
// 560.976 us; speedup vs baseline: 3.2484x; 3.2484x over previous
//
#include <hip/hip_runtime.h>
#include <hip/hip_bf16.h>
#include <math.h>
#include <stdint.h>

#define N_NODES 100000
#define N_EDGES 3200000
#define D 64
#define NUM_RELS 20
#define HID_ATTR 32
#define OUT_ATTR 10
#define PADR 72                          // A-tile row stride in bf16 (144 B)
#define NFB (N_NODES / 16)               // 6250 fused blocks (16 nodes each)

// two-level MSD counting sort (R8 structure, best measured)
#define BUCKET_DSTS 256                  // dsts per coarse bucket (dst >> 8)
#define NB 391                           // ceil(100000 / 256)
#define PA_THREADS 512
#define PA_EPT 16                        // edges per thread
#define PA_CHUNK (PA_THREADS * PA_EPT)   // 8192
#define PA_GRID 391                      // ceil(3.2M / 8192)
#define PB_BINS (BUCKET_DSTS * NUM_RELS) // 5120 fine bins per bucket

// prep kernel block partition: [0,NB) hist | [NB,NB+F2B) f2b | wconv
#define F2B_BLOCKS 3125                  // 1,600,000 float4 / 512
#define WC_BLOCKS (2 * NUM_RELS)
#define PREP_GRID (NB + F2B_BLOCKS + WC_BLOCKS)

typedef __attribute__((ext_vector_type(8))) short bf16x8;
typedef __attribute__((ext_vector_type(4))) float f32x4;

static __device__ __forceinline__ unsigned short f2bf(float x) {
    unsigned u = __builtin_bit_cast(unsigned, x);
    unsigned r = (u + 0x7FFFu + ((u >> 16) & 1u)) >> 16;
    return (unsigned short)r;
}
static __device__ __forceinline__ float bf2f_lo(unsigned u) {
    return __builtin_bit_cast(float, u << 16);
}
static __device__ __forceinline__ float bf2f_hi(unsigned u) {
    return __builtin_bit_cast(float, u & 0xFFFF0000u);
}
// packed f32->bf16 RNE (bit-identical to f2bf above for finite inputs)
static __device__ __forceinline__ unsigned cvt_pk_bf16(float lo, float hi) {
    unsigned r;
    asm("v_cvt_pk_bf16_f32 %0, %1, %2" : "=v"(r) : "v"(lo), "v"(hi));
    return r;
}

// ---------------- prep: hist + f2b + wconv in ONE launch (independent work)
// R12 measured: this merge saves ~25-30 us of launch/tail time vs 3 kernels.
__global__ __launch_bounds__(512) void prep_kernel(
    const int* __restrict__ dst, int* __restrict__ hist,
    const float* __restrict__ hin, unsigned short* __restrict__ xb,
    const float* __restrict__ W1, const float* __restrict__ W2,
    unsigned short* __restrict__ w1b, unsigned short* __restrict__ w2b) {
    int bid = blockIdx.x;
    if (bid < NB) {
        // ---- histogram of dst>>8 over this block's edge chunk
        __shared__ int h[NB];
        for (int i = threadIdx.x; i < NB; i += 512) h[i] = 0;
        __syncthreads();
        int base = bid * PA_CHUNK;
#pragma unroll
        for (int k = 0; k < PA_EPT; ++k) {
            int e = base + k * 512 + threadIdx.x;
            if (e < N_EDGES) atomicAdd(&h[dst[e] >> 8], 1);
        }
        __syncthreads();
        for (int i = threadIdx.x; i < NB; i += 512)
            if (h[i]) atomicAdd(&hist[i], h[i]);
    } else if (bid < NB + F2B_BLOCKS) {
        // ---- f32 -> bf16 node features (float4 granularity)
        int i = (bid - NB) * 512 + threadIdx.x;   // < 1,600,000 exactly
        float4 v = ((const float4*)hin)[i];
        ushort4 o;
        o.x = f2bf(v.x); o.y = f2bf(v.y); o.z = f2bf(v.z); o.w = f2bf(v.w);
        ((ushort4*)xb)[i] = o;
    } else {
        // ---- W[r][d][o] fp32 -> Wb[r][o][d] bf16 (B-frag layout, verified)
        int r = bid - (NB + F2B_BLOCKS);
        const float* Ws = (r < NUM_RELS) ? W1 + (size_t)r * (D * D)
                                         : W2 + (size_t)(r - NUM_RELS) * (D * D);
        unsigned short* Wd = (r < NUM_RELS) ? w1b + (size_t)r * (D * D)
                                            : w2b + (size_t)(r - NUM_RELS) * (D * D);
        for (int i = threadIdx.x; i < D * D; i += 512) {
            int d2 = i >> 6, o = i & 63;
            Wd[o * D + d2] = f2bf(Ws[d2 * D + o]);
        }
    }
}

// ---------------- scan of 391 bucket counts; also zeroes gsum ----
__global__ void scan_bucket_kernel(const int* __restrict__ hist, int* __restrict__ bbase,
                                   int* __restrict__ bcur, int* __restrict__ sched_off,
                                   int* __restrict__ gsum_i) {
    __shared__ int s[512];
    int t = threadIdx.x;
    if (t < 64) gsum_i[t] = 0;
    int v = (t < NB) ? hist[t] : 0;
    s[t] = v;
    __syncthreads();
    for (int d2 = 1; d2 < 512; d2 <<= 1) {
        int x = (t >= d2) ? s[t - d2] : 0;
        __syncthreads();
        s[t] += x;
        __syncthreads();
    }
    if (t < NB) {
        int b = s[t] - v;
        bbase[t] = b;
        bcur[t] = b;
    }
    if (t == 0) {
        bbase[NB] = N_EDGES;
        sched_off[NFB * 32] = N_EDGES;   // global sentinel
    }
}

__global__ __launch_bounds__(PA_THREADS) void passA_kernel(
    const int* __restrict__ src, const int* __restrict__ dst,
    const int* __restrict__ etype, int* __restrict__ bcur,
    unsigned* __restrict__ tmp) {
    __shared__ int h[NB];   // block histogram
    __shared__ int gb[NB];  // global segment base for this block
    __shared__ int c[NB];   // running within-segment count
    for (int i = threadIdx.x; i < NB; i += PA_THREADS) h[i] = 0;
    __syncthreads();
    int base = blockIdx.x * PA_CHUNK;
    int d[PA_EPT];
#pragma unroll
    for (int k = 0; k < PA_EPT; ++k) {
        int e = base + k * PA_THREADS + threadIdx.x;
        d[k] = (e < N_EDGES) ? dst[e] : -1;
        if (d[k] >= 0) atomicAdd(&h[d[k] >> 8], 1);
    }
    __syncthreads();
    for (int i = threadIdx.x; i < NB; i += PA_THREADS) {
        int n = h[i];
        gb[i] = n ? atomicAdd(&bcur[i], n) : 0;
        c[i] = 0;
    }
    __syncthreads();
#pragma unroll
    for (int k = 0; k < PA_EPT; ++k) {
        int e = base + k * PA_THREADS + threadIdx.x;
        if (d[k] >= 0) {
            int b = d[k] >> 8;
            int sv = src[e], r = etype[e];
            int pos = gb[b] + atomicAdd(&c[b], 1);
            tmp[pos] = ((unsigned)(d[k] & 255) << 22) | ((unsigned)sv << 5) | (unsigned)r;
        }
    }
}

__global__ __launch_bounds__(512) void passB_kernel(
    const unsigned* __restrict__ tmp, const int* __restrict__ bbase,
    unsigned* __restrict__ edgedata, int* __restrict__ sched_off) {
    __shared__ int binpos[PB_BINS];   // 20 KB: counts -> scheduled positions
    __shared__ int blen[PB_BINS];     // 20 KB: bin lengths (saved counts)
    __shared__ unsigned sk[16 * 64];  // 4 KB: per-fb sort keys (len<<8|wloc)
    __shared__ int swo[16 * 64];      // 4 KB: per-walk scheduled offset in fb
    __shared__ int gs[512];           // 2 KB: per-fb group-total scan
    __shared__ int ssum[512];         // 2 KB: bin scan partials
    __shared__ int fbb[16];           // fb base positions
    int t = threadIdx.x;
    int b = blockIdx.x;
    int beg = bbase[b], end = bbase[b + 1];
    for (int i = t; i < PB_BINS; i += 512) binpos[i] = 0;
    __syncthreads();
    for (int i = beg + t; i < end; i += 512) {
        unsigned v = tmp[i];
        int key = (int)(v >> 22) * NUM_RELS + (int)(v & 31u);
        atomicAdd(&binpos[key], 1);
    }
    __syncthreads();
    for (int i = t; i < PB_BINS; i += 512) blen[i] = binpos[i];
    __syncthreads();
    // exclusive scan of 5120 bins; thread t owns bins [t*10, t*10+10)
    int loc[10];
    int sum = 0;
#pragma unroll
    for (int j = 0; j < 10; ++j) {
        loc[j] = sum;
        sum += binpos[t * 10 + j];
    }
    ssum[t] = sum;
    __syncthreads();
    for (int d2 = 1; d2 < 512; d2 <<= 1) {
        int x = (t >= d2) ? ssum[t - d2] : 0;
        __syncthreads();
        ssum[t] += x;
        __syncthreads();
    }
    int tbase = beg + ((t > 0) ? ssum[t - 1] : 0);
#pragma unroll
    for (int j = 0; j < 10; ++j) binpos[t * 10 + j] = tbase + loc[j];
    __syncthreads();
    if (t < 16) fbb[t] = binpos[t * 320];
    __syncthreads();
    // walk lengths: walk = (node_local nl, quarter qt), wloc = nl*4+qt
    for (int w = t; w < 1024; w += 512) {
        int fb = w >> 6, wloc = w & 63;
        int nl = wloc >> 2, qt = wloc & 3;
        int b0 = (fb * 16 + nl) * NUM_RELS + qt * 5;
        int len = blen[b0] + blen[b0 + 1] + blen[b0 + 2] + blen[b0 + 3] + blen[b0 + 4];
        sk[fb * 64 + wloc] = ((unsigned)len << 8) | (unsigned)wloc;
    }
    // bitonic sort desc, 64 elements per fb, 32 comparators per fb
    {
        int fb = t >> 5, k = t & 31;
        unsigned* s = &sk[fb * 64];
        for (int size = 2; size <= 64; size <<= 1) {
            for (int stride = size >> 1; stride > 0; stride >>= 1) {
                __syncthreads();
                int i1 = ((k & ~(stride - 1)) << 1) | (k & (stride - 1));
                int i2 = i1 | stride;
                unsigned x = s[i1], y = s[i2];
                bool descb = (i1 & size) == 0;
                if (descb ? (x < y) : (x > y)) { s[i1] = y; s[i2] = x; }
            }
        }
    }
    __syncthreads();
    // fold-pair rank k with rank 63-k onto group slot k; scan group totals
    {
        int fb = t >> 5, k = t & 31;
        unsigned kA = sk[fb * 64 + k], kB = sk[fb * 64 + 63 - k];
        int lenA = (int)(kA >> 8), widA = (int)(kA & 63u);
        int lenB = (int)(kB >> 8), widB = (int)(kB & 63u);
        int tot = lenA + lenB;
        gs[t] = tot;
        __syncthreads();
        for (int d2 = 1; d2 < 32; d2 <<= 1) {
            int x = (k >= d2) ? gs[t - d2] : 0;
            __syncthreads();
            gs[t] += x;
            __syncthreads();
        }
        int gbase = gs[t] - tot;   // exclusive within fb
        swo[fb * 64 + widA] = gbase;
        swo[fb * 64 + widB] = gbase + lenA;
        int gfb = b * 16 + fb;
        if (gfb < NFB) sched_off[gfb * 32 + k] = fbb[fb] + gbase;
    }
    __syncthreads();
    // rewrite binpos to scheduled positions
    for (int i = t; i < PB_BINS; i += 512) {
        int node = i / 20, rel = i - node * 20;
        int fb = node >> 4, nl = node & 15;
        int qt = rel / 5, rr = rel - qt * 5;
        int wid = nl * 4 + qt;
        int base = fbb[fb] + swo[fb * 64 + wid];
        int b0 = node * 20 + qt * 5;
        for (int r = 0; r < rr; ++r) base += blen[b0 + r];
        binpos[i] = base;
    }
    __syncthreads();
    // scatter in schedule order with rowoff payload
    for (int i = beg + t; i < end; i += 512) {
        unsigned v = tmp[i];
        int dl = (int)(v >> 22), rel = (int)(v & 31u);
        int ro = rel * (16 * PADR) + (dl & 15) * PADR;
        int key = dl * NUM_RELS + rel;
        int pos = atomicAdd(&binpos[key], 1);
        edgedata[pos] = ((v >> 5) & 0x1FFFFu) | ((unsigned)ro << 17);
    }
}

// ---------------- fused layer (exact R8 version — best measured, 172 us) --
// Block = 16 dst nodes (= one fb), 8 waves. Group gidx = wave*4+grp in [0,32)
// processes the contiguous balanced span [sched_off[fb*32+gidx], +1) of
// schedule-ordered edges. Edge word carries its A-row offset ro = w>>17;
// run-reset key is ro (runs never straddle spans). The random x-row gather
// is memory-system-bound (R5-R10 arc: occupancy/pipelining/staging all
// neutral-or-negative); structure frozen. R12 lesson: NO per-block
// __threadfence / last-block readout — device fences per block cost ~1.3 ms.
// Tail merged via clamp-to-endm1 + x=0 masking -> bit-identical numerics.
// Waves 0-3 then do the 40-MFMA transform (verified layouts).
// mode 1: relu'd bf16; mode 2: fp32.
__global__ __launch_bounds__(512, 6) void fused_layer(
    const unsigned short* __restrict__ xb, const unsigned short* __restrict__ Wb,
    const unsigned* __restrict__ edgedata, const int* __restrict__ sched_off,
    unsigned short* __restrict__ xbout, float* __restrict__ h2out, int mode) {
    __shared__ __align__(16) unsigned short A[NUM_RELS * 16 * PADR];  // 46080 B
    int wave = threadIdx.x >> 6, lane = threadIdx.x & 63;
    int grp = lane >> 4, l4 = lane & 15;
    int gidx = wave * 4 + grp;         // 0..31
    int colb = l4 * 4;                 // column base, 0..60

    int beg = sched_off[blockIdx.x * 32 + gidx];
    int end = sched_off[blockIdx.x * 32 + gidx + 1];

    for (int i = threadIdx.x; i < NUM_RELS * 16 * PADR / 8; i += 512)
        ((int4*)A)[i] = (int4){0, 0, 0, 0};

    int cnt = end - beg;
    int nb = (cnt + 3) >> 2;           // number of (padded) 4-edge batches
    int nbmax = max(nb, __shfl_xor(nb, 16));
    nbmax = max(nbmax, __shfl_xor(nbmax, 32));
    int endm1 = end - 1;

    float a0 = 0.f, a1 = 0.f, a2 = 0.f, a3 = 0.f;
    unsigned roprev = 0xFFFFFFFFu;
    unsigned short* Ac = A + (unsigned)colb;

    auto rowload = [&](unsigned ewv) -> uint2 {
        return *(const uint2*)(xb + ((ewv & 0x1FFFFu) << 6) + (unsigned)colb);
    };
    auto proc = [&](const unsigned (&ewc)[4], const uint2 (&xv)[4], int valid) {
#pragma unroll
        for (int j = 0; j < 4; ++j) {
            unsigned ro = ewc[j] >> 17;
            bool real = j < valid;
            unsigned mx = real ? xv[j].x : 0u;
            unsigned my = real ? xv[j].y : 0u;
            bool keep = (ro == roprev);
            a0 = (keep ? a0 : 0.f) + bf2f_lo(mx);
            a1 = (keep ? a1 : 0.f) + bf2f_hi(mx);
            a2 = (keep ? a2 : 0.f) + bf2f_lo(my);
            a3 = (keep ? a3 : 0.f) + bf2f_hi(my);
            uint2 o;
            o.x = cvt_pk_bf16(a0, a1);
            o.y = cvt_pk_bf16(a2, a3);
            *(uint2*)(Ac + ro) = o;
            roprev = ro;
        }
    };

    unsigned e0[4], e1[4], e2[4];
    uint2 v0[4], v1[4];
    if (nb > 0) {
#pragma unroll
        for (int j = 0; j < 4; ++j) e0[j] = edgedata[min(beg + j, endm1)];
    }
    if (nb > 1) {
#pragma unroll
        for (int j = 0; j < 4; ++j) e1[j] = edgedata[min(beg + 4 + j, endm1)];
    }
    if (nb > 2) {
#pragma unroll
        for (int j = 0; j < 4; ++j) e2[j] = edgedata[min(beg + 8 + j, endm1)];
    }
    if (nb > 0) {
#pragma unroll
        for (int j = 0; j < 4; ++j) v0[j] = rowload(e0[j]);
    }
    if (nb > 1) {
#pragma unroll
        for (int j = 0; j < 4; ++j) v1[j] = rowload(e1[j]);
    }
    __builtin_amdgcn_sched_barrier(0);
    __syncthreads();

#define PHASE(GG, EW0, EW2, XV0)                                              \
    {                                                                         \
        int gg = (GG);                                                        \
        if (gg < nbmax) {                                                     \
            unsigned ewc[4];                                                  \
            uint2 xvc[4];                                                     \
            _Pragma("unroll") for (int j = 0; j < 4; ++j) {                   \
                ewc[j] = EW0[j]; xvc[j] = XV0[j];                             \
            }                                                                 \
            if (gg + 3 < nb) {                                                \
                int lb = beg + (gg + 3) * 4;                                  \
                _Pragma("unroll") for (int j = 0; j < 4; ++j)                 \
                    EW0[j] = edgedata[min(lb + j, endm1)];                    \
            }                                                                 \
            if (gg + 2 < nb) {                                                \
                _Pragma("unroll") for (int j = 0; j < 4; ++j)                 \
                    XV0[j] = rowload(EW2[j]);                                 \
            }                                                                 \
            __builtin_amdgcn_sched_barrier(0);                                \
            if (gg < nb) proc(ewc, xvc, cnt - gg * 4);                        \
        }                                                                     \
    }

    for (int g = 0; g < nbmax; g += 6) {
        PHASE(g + 0, e0, e2, v0)
        PHASE(g + 1, e1, e0, v1)
        PHASE(g + 2, e2, e1, v0)
        PHASE(g + 3, e0, e2, v1)
        PHASE(g + 4, e1, e0, v0)
        PHASE(g + 5, e2, e1, v1)
    }
#undef PHASE
    __syncthreads();

    // waves 0-3: transform. wave w covers output columns w*16..w*16+15
    if (wave < 4) {
        int lrow = lane & 15, lhi = lane >> 4;
        f32x4 C = {0.f, 0.f, 0.f, 0.f};
        for (int q = 0; q < NUM_RELS; ++q) {
            const unsigned short* Arow = &A[(q * 16 + lrow) * PADR + lhi * 8];
            bf16x8 aa0 = *(const bf16x8*)(Arow);        // k = lhi*8 + j
            bf16x8 aa1 = *(const bf16x8*)(Arow + 32);   // k = 32 + lhi*8 + j
            const unsigned short* wrow = Wb + ((size_t)q << 12)
                                         + (size_t)(wave * 16 + lrow) * D + lhi * 8;
            bf16x8 b0 = *(const bf16x8*)(wrow);
            bf16x8 b1 = *(const bf16x8*)(wrow + 32);
            C = __builtin_amdgcn_mfma_f32_16x16x32_bf16(aa0, b0, C, 0, 0, 0);
            C = __builtin_amdgcn_mfma_f32_16x16x32_bf16(aa1, b1, C, 0, 0, 0);
        }
        // C/D: row = lhi*4 + reg (dst-local), col = wave*16 + lrow
#pragma unroll
        for (int reg = 0; reg < 4; ++reg) {
            int onode = blockIdx.x * 16 + lhi * 4 + reg;
            int col = wave * 16 + lrow;
            if (mode == 1)
                xbout[(size_t)onode * D + col] = f2bf(fmaxf(C[reg], 0.f));
            else
                h2out[(size_t)onode * D + col] = C[reg];
        }
    }
}

// ---------------- readout ----------------

__global__ void colsum_kernel(const float* __restrict__ h2,
                              float* __restrict__ g, int n) {
    __shared__ float s[256];
    int tid = threadIdx.x;
    int col = tid & 63;
    int rowgrp = (blockIdx.x * blockDim.x + tid) >> 6;
    int nrowgrp = (gridDim.x * blockDim.x) >> 6;
    float acc = 0.0f;
    for (int row = rowgrp; row < n; row += nrowgrp)
        acc += h2[(size_t)row * D + col];
    s[tid] = acc;
    __syncthreads();
    if (tid < 64) {
        acc = s[tid] + s[tid + 64] + s[tid + 128] + s[tid + 192];
        atomicAdd(&g[col], acc);
    }
}

__global__ void mlp_kernel(const float* __restrict__ g,
                           const float* __restrict__ A1w,
                           const float* __restrict__ A1b,
                           const float* __restrict__ A2w,
                           const float* __restrict__ A2b,
                           float* __restrict__ out, float invN) {
    __shared__ float a1[HID_ATTR];
    int t = threadIdx.x;
    if (t < HID_ATTR) {
        float acc = A1b[t];
#pragma unroll
        for (int d2 = 0; d2 < D; ++d2)
            acc = fmaf(g[d2] * invN, A1w[d2 * HID_ATTR + t], acc);
        a1[t] = fmaxf(acc, 0.0f);
    }
    __syncthreads();
    if (t < OUT_ATTR) {
        float acc = A2b[t];
#pragma unroll
        for (int j = 0; j < HID_ATTR; ++j)
            acc = fmaf(a1[j], A2w[j * OUT_ATTR + t], acc);
        out[t] = 1.0f / (1.0f + expf(-acc));
    }
}

// ---------------- launch ----------------

extern "C" void kernel_launch(void* const* d_in, const int* in_sizes, int n_in,
                              void* d_out, int out_size, void* d_ws, size_t ws_size,
                              hipStream_t stream) {
    const float* h   = (const float*)d_in[0];
    const int* src   = (const int*)d_in[1];
    const int* dst   = (const int*)d_in[2];
    const int* etype = (const int*)d_in[3];
    const float* W1  = (const float*)d_in[4];
    const float* W2  = (const float*)d_in[5];
    const float* A1w = (const float*)d_in[6];
    const float* A1b = (const float*)d_in[7];
    const float* A2w = (const float*)d_in[8];
    const float* A2b = (const float*)d_in[9];

    float* out_h2 = (float*)d_out;
    float* out_a  = out_h2 + (size_t)N_NODES * D;

    // workspace layout (int offsets from d_ws; all buffers 16B-aligned)
    int* base       = (int*)d_ws;
    float* gsum     = (float*)base;               // 64 f32
    int* hist_b     = base + 64;                  // 448 (NB padded)
    int* bbase      = base + 512;                 // 448 (NB+1)
    int* bcur       = base + 960;                 // 448
    int* sched_off  = base + 1408;                // 200,064 (NFB*32+1 padded)
    unsigned* tmp   = (unsigned*)(base + 201472); // 3,200,000
    unsigned* edgedata = (unsigned*)(base + 3401472); // 3,200,000
    unsigned short* xb  = (unsigned short*)(base + 6601472);   // 6.4M u16
    unsigned short* xb2 = (unsigned short*)(base + 9801472);   // 6.4M u16
    unsigned short* w1b = (unsigned short*)(base + 13001472);  // 81,920 u16
    unsigned short* w2b = (unsigned short*)(base + 13042432);  // 81,920 u16
    // total: 13,083,392 ints = 52.3 MB

    hipMemsetAsync(hist_b, 0, NB * sizeof(int), stream);

    // prep: histogram + f2b + wconv (independent work, one launch)
    prep_kernel<<<PREP_GRID, 512, 0, stream>>>(dst, hist_b, h, xb,
                                               W1, W2, w1b, w2b);
    // scan (also zeroes gsum)
    scan_bucket_kernel<<<1, 512, 0, stream>>>(hist_b, bbase, bcur, sched_off,
                                              (int*)gsum);
    passA_kernel<<<PA_GRID, PA_THREADS, 0, stream>>>(src, dst, etype, bcur, tmp);
    passB_kernel<<<NB, 512, 0, stream>>>(tmp, bbase, edgedata, sched_off);

    // two fused RGCN layers
    fused_layer<<<NFB, 512, 0, stream>>>(xb, w1b, edgedata, sched_off,
                                         xb2, nullptr, 1);
    fused_layer<<<NFB, 512, 0, stream>>>(xb2, w2b, edgedata, sched_off,
                                         nullptr, out_h2, 2);

    // readout
    colsum_kernel<<<512, 256, 0, stream>>>(out_h2, gsum, N_NODES);
    mlp_kernel<<<1, 64, 0, stream>>>(gsum, A1w, A1b, A2w, A2b,
                                     out_a, 1.0f / (float)N_NODES);
}